// Round 7
// baseline (1553.146 us; speedup 1.0000x reference)
//
#include <hip/hip_runtime.h>
#include <hip/hip_bf16.h>
#include <cstdint>
#include <cstddef>

// ---------------------------------------------------------------------------
// EnrichAttention: B=32, L1=L2=512, H=A=256, 3H=768, 2H=512
// R7: GRU with TRUE register-resident whh: 256 thr/WG (1 wave/SIMD, ~512-reg
//     budget), 3 rows/thread as 96 named SSA H2x4 values (384 VGPRs), zero
//     per-step weight traffic, one barrier/step. GEMMs identical to R5/R6.
// ---------------------------------------------------------------------------

typedef _Float16 h2 __attribute__((ext_vector_type(2)));
typedef short s8v __attribute__((ext_vector_type(8)));    // 8 bf16 (4 VGPRs)
typedef float f4v __attribute__((ext_vector_type(4)));    // MFMA accumulator
struct alignas(16) H2x4 { h2 a, b, c, d; };

#if __has_builtin(__builtin_amdgcn_fdot2)
#define FDOT2(a, b, c) __builtin_amdgcn_fdot2((a), (b), (c), false)
#else
#define FDOT2(a, b, c) ((c) + (float)(a)[0] * (float)(b)[0] + (float)(a)[1] * (float)(b)[1])
#endif

#if __has_builtin(__builtin_amdgcn_sched_barrier)
#define SCHED_FENCE() __builtin_amdgcn_sched_barrier(0)
#else
#define SCHED_FENCE() asm volatile("" ::: "memory")
#endif

// Workgroup barrier waiting only on LDS (lgkmcnt). Only the LDS h buffer
// carries cross-thread deps in the GRU loop. (Validated R2/R5/R6.)
__device__ __forceinline__ void bar_lds() {
    asm volatile("s_waitcnt lgkmcnt(0)\n\ts_barrier" ::: "memory");
}

__device__ __forceinline__ float fast_exp(float x) {
#if __has_builtin(__builtin_amdgcn_exp2f)
    return __builtin_amdgcn_exp2f(x * 1.44269504f);
#else
    return __expf(x);
#endif
}
__device__ __forceinline__ float fast_rcp(float x) {
#if __has_builtin(__builtin_amdgcn_rcpf)
    return __builtin_amdgcn_rcpf(x);
#else
    return 1.f / x;
#endif
}
__device__ __forceinline__ float fast_sig(float x) { return fast_rcp(1.f + fast_exp(-x)); }
__device__ __forceinline__ float fast_tanh(float x) {
    return 1.f - 2.f * fast_rcp(1.f + fast_exp(2.f * x));
}

// ---------------------------------------------------------------------------
// MFMA bf16 NT GEMM (verified R5): C[M,N] = A[M,K] * B[N,K]^T.
// ---------------------------------------------------------------------------
__global__ __launch_bounds__(256) void gemm_bf16(
    const __hip_bfloat16* __restrict__ A, int lda, long long sA,
    const __hip_bfloat16* __restrict__ B, int ldb, long long sB,
    void* __restrict__ C, int ldc, long long sC,
    int K,
    const float* __restrict__ bias,
    const float* __restrict__ emul, int ldmul,
    int relu, int accum, int out_bf16)
{
    __shared__ short As[128][40];
    __shared__ short Bs[128][40];

    const int tid  = threadIdx.x;
    const int wave = tid >> 6, lane = tid & 63;
    const int quad = lane >> 4, l16 = lane & 15;
    const int wrow = (wave >> 1) * 64, wcol = (wave & 1) * 64;
    const int m0 = blockIdx.y * 128, n0 = blockIdx.x * 128;

    const short* Ab = (const short*)A + (size_t)blockIdx.z * sA;
    const short* Bb = (const short*)B + (size_t)blockIdx.z * sB;

    f4v acc[4][4];
#pragma unroll
    for (int i = 0; i < 4; ++i)
#pragma unroll
        for (int j = 0; j < 4; ++j) acc[i][j] = 0.f;

    const int r0 = tid >> 2,        s0 = (tid & 3) * 8;
    const int r1 = (tid + 256) >> 2, s1 = ((tid + 256) & 3) * 8;

    for (int k0 = 0; k0 < K; k0 += 32) {
        *(s8v*)&As[r0][s0] = *(const s8v*)(Ab + (size_t)(m0 + r0) * lda + k0 + s0);
        *(s8v*)&As[r1][s1] = *(const s8v*)(Ab + (size_t)(m0 + r1) * lda + k0 + s1);
        *(s8v*)&Bs[r0][s0] = *(const s8v*)(Bb + (size_t)(n0 + r0) * ldb + k0 + s0);
        *(s8v*)&Bs[r1][s1] = *(const s8v*)(Bb + (size_t)(n0 + r1) * ldb + k0 + s1);
        __syncthreads();

        s8v af[4], bf[4];
#pragma unroll
        for (int i = 0; i < 4; ++i)
            af[i] = *(const s8v*)&As[wrow + i * 16 + l16][quad * 8];
#pragma unroll
        for (int j = 0; j < 4; ++j)
            bf[j] = *(const s8v*)&Bs[wcol + j * 16 + l16][quad * 8];
#pragma unroll
        for (int i = 0; i < 4; ++i)
#pragma unroll
            for (int j = 0; j < 4; ++j)
                acc[i][j] = __builtin_amdgcn_mfma_f32_16x16x32_bf16(
                    af[i], bf[j], acc[i][j], 0, 0, 0);
        __syncthreads();
    }

    float* Cf = (float*)C + (size_t)blockIdx.z * sC;
    __hip_bfloat16* Cb = (__hip_bfloat16*)C + (size_t)blockIdx.z * sC;
#pragma unroll
    for (int i = 0; i < 4; ++i)
#pragma unroll
        for (int j = 0; j < 4; ++j)
#pragma unroll
            for (int r = 0; r < 4; ++r) {
                const int m = m0 + wrow + i * 16 + quad * 4 + r;
                const int n = n0 + wcol + j * 16 + l16;
                float v = acc[i][j][r];
                if (bias)  v += bias[n];
                if (accum) v += Cf[(size_t)m * ldc + n];
                if (emul)  v *= emul[(size_t)m * ldmul + n];
                if (relu)  v = fmaxf(v, 0.f);
                if (out_bf16) Cb[(size_t)m * ldc + n] = __float2bfloat16(v);
                else          Cf[(size_t)m * ldc + n] = v;
            }
}

// fp32 -> bf16 elementwise (n % 4 == 0)
__global__ __launch_bounds__(256) void f2b(
    const float* __restrict__ s, __hip_bfloat16* __restrict__ d, int n)
{
    const int i = (blockIdx.x * 256 + threadIdx.x) * 4;
    if (i < n) {
        float4 v = *(const float4*)(s + i);
        d[i + 0] = __float2bfloat16(v.x);
        d[i + 1] = __float2bfloat16(v.y);
        d[i + 2] = __float2bfloat16(v.z);
        d[i + 3] = __float2bfloat16(v.w);
    }
}

// fp32 [Z][R][C] -> bf16 [Z][C][R] tiled transpose
__global__ __launch_bounds__(256) void tr_f2b(
    const float* __restrict__ src, __hip_bfloat16* __restrict__ dst,
    int R, int C, long long sS, long long sD)
{
    __shared__ float t[32][33];
    const int r0 = blockIdx.y * 32, c0 = blockIdx.x * 32;
    const int tx = threadIdx.x & 31, ty = threadIdx.x >> 5;
    const float* S = src + (size_t)blockIdx.z * sS;
    __hip_bfloat16* Dd = dst + (size_t)blockIdx.z * sD;
#pragma unroll
    for (int i = 0; i < 32; i += 8)
        t[ty + i][tx] = S[(size_t)(r0 + ty + i) * C + c0 + tx];
    __syncthreads();
#pragma unroll
    for (int i = 0; i < 32; i += 8)
        Dd[(size_t)(c0 + ty + i) * R + r0 + tx] = __float2bfloat16(t[tx][ty + i]);
}

// softmax over axis=1 (i) for each (b, j): fp32 in, bf16 out
__global__ __launch_bounds__(256) void softmax_dim1(
    const float* __restrict__ Mf, __hip_bfloat16* __restrict__ Ms)
{
    const int j = blockIdx.x * 256 + threadIdx.x;
    const float* base = Mf + (size_t)blockIdx.y * 262144;
    __hip_bfloat16* ob = Ms + (size_t)blockIdx.y * 262144;

    float mx = -1e30f;
    for (int i = 0; i < 512; ++i)
        mx = fmaxf(mx, base[(size_t)i * 512 + j]);
    float s = 0.f;
    for (int i = 0; i < 512; ++i)
        s += __expf(base[(size_t)i * 512 + j] - mx);
    const float inv = 1.f / s;
    for (int i = 0; i < 512; ++i)
        ob[(size_t)i * 512 + j] =
            __float2bfloat16(__expf(base[(size_t)i * 512 + j] - mx) * inv);
}

// ---------------------------------------------------------------------------
// GRU R7: one WG (256 threads, 4 waves, 1/SIMD) per batch. Thread o owns whh
// rows {o, o+256, o+512} as 96 named SSA H2x4 values -> VGPR/AGPR resident.
// Thread o computes hr/hz/hn for hidden dim o locally: no hp exchange, all
// threads run gates, one lgkm barrier per step, double-buffered f16 h in LDS.
// ---------------------------------------------------------------------------
#define FOR32(M, R) \
  M(0,R) M(1,R) M(2,R) M(3,R) M(4,R) M(5,R) M(6,R) M(7,R) \
  M(8,R) M(9,R) M(10,R) M(11,R) M(12,R) M(13,R) M(14,R) M(15,R) \
  M(16,R) M(17,R) M(18,R) M(19,R) M(20,R) M(21,R) M(22,R) M(23,R) \
  M(24,R) M(25,R) M(26,R) M(27,R) M(28,R) M(29,R) M(30,R) M(31,R)

// load + f16-pack pairs 8K..8K+7 of row R into named value WR_K
#define LW(K, R) \
  H2x4 W##R##_##K; { \
    float4 q0 = wrp##R[2*(K)], q1 = wrp##R[2*(K)+1]; \
    W##R##_##K.a[0]=(_Float16)q0.x; W##R##_##K.a[1]=(_Float16)q0.y; \
    W##R##_##K.b[0]=(_Float16)q0.z; W##R##_##K.b[1]=(_Float16)q0.w; \
    W##R##_##K.c[0]=(_Float16)q1.x; W##R##_##K.c[1]=(_Float16)q1.y; \
    W##R##_##K.d[0]=(_Float16)q1.z; W##R##_##K.d[1]=(_Float16)q1.w; } \
  if (((K) & 3) == 3) SCHED_FENCE();

// one h-chunk (8 dims) dotted into all 3 rows' accumulators (12 fdot2)
#define DOT3(K, R) { H2x4 v = hvv[K]; \
    a00 = FDOT2(W0_##K.a, v.a, a00); a01 = FDOT2(W0_##K.b, v.b, a01); \
    a02 = FDOT2(W0_##K.c, v.c, a02); a03 = FDOT2(W0_##K.d, v.d, a03); \
    a10 = FDOT2(W1_##K.a, v.a, a10); a11 = FDOT2(W1_##K.b, v.b, a11); \
    a12 = FDOT2(W1_##K.c, v.c, a12); a13 = FDOT2(W1_##K.d, v.d, a13); \
    a20 = FDOT2(W2_##K.a, v.a, a20); a21 = FDOT2(W2_##K.b, v.b, a21); \
    a22 = FDOT2(W2_##K.c, v.c, a22); a23 = FDOT2(W2_##K.d, v.d, a23); }

__global__ __launch_bounds__(256, 1) void gru_kernel(
    const float* __restrict__ xproj,   // [B, T, 768]
    const float* __restrict__ whh,     // [768, 256]
    const float* __restrict__ bhh,     // [768]
    float* __restrict__ out)           // [B, T, 256]
{
    const int b = blockIdx.x;
    const int o = threadIdx.x;

    __shared__ __align__(16) _Float16 hsh[2][256];   // h state, double-buffered

    const float4* wrp0 = (const float4*)(whh + (size_t)o * 256);
    const float4* wrp1 = (const float4*)(whh + (size_t)(o + 256) * 256);
    const float4* wrp2 = (const float4*)(whh + (size_t)(o + 512) * 256);
    FOR32(LW, 0)
    FOR32(LW, 1)
    FOR32(LW, 2)

    const float b0 = bhh[o], b1 = bhh[o + 256], b2 = bhh[o + 512];
    const float* xb = xproj + (size_t)b * 512 * 768;

    hsh[0][o] = (_Float16)0.f;
    float hprev = 0.f;
    float xr = xb[o], xz = xb[256 + o], xn = xb[512 + o];
    bar_lds();

    for (int t = 0; t < 512; ++t) {
        const H2x4* hvv = (const H2x4*)hsh[t & 1];
        float a00 = 0.f, a01 = 0.f, a02 = 0.f, a03 = 0.f;
        float a10 = 0.f, a11 = 0.f, a12 = 0.f, a13 = 0.f;
        float a20 = 0.f, a21 = 0.f, a22 = 0.f, a23 = 0.f;
        FOR32(DOT3, _)

        // prefetch x-projections for step t+1 (overlaps gate math)
        const int tn = (t + 1) & 511;
        const float* xbn = xb + (size_t)tn * 768;
        float nr = xbn[o], nz = xbn[256 + o], nn2 = xbn[512 + o];

        const float hr = b0 + (a00 + a01) + (a02 + a03);
        const float hz = b1 + (a10 + a11) + (a12 + a13);
        const float hn = b2 + (a20 + a21) + (a22 + a23);
        const float r = fast_sig(xr + hr);
        const float z = fast_sig(xz + hz);
        const float n = fast_tanh(xn + r * hn);
        const float hnew = (1.f - z) * n + z * hprev;
        hprev = hnew;

        hsh[(t + 1) & 1][o] = (_Float16)hnew;
        out[((size_t)b * 512 + t) * 256 + o] = hnew;
        xr = nr; xz = nz; xn = nn2;
        bar_lds();
    }
}

extern "C" void kernel_launch(void* const* d_in, const int* in_sizes, int n_in,
                              void* d_out, int out_size, void* d_ws, size_t ws_size,
                              hipStream_t stream)
{
    (void)in_sizes; (void)n_in; (void)out_size; (void)ws_size;

    const float* x1  = (const float*)d_in[0];   // [32,512,256]
    const float* x2  = (const float*)d_in[1];   // [32,512,256]
    const float* w1  = (const float*)d_in[2];   // [256,256]
    const float* w2  = (const float*)d_in[3];   // [256,256]
    const float* Dm  = (const float*)d_in[4];   // [256,256]
    const float* Wm  = (const float*)d_in[5];   // [512,512]
    const float* wih = (const float*)d_in[6];   // [768,512]
    const float* whh = (const float*)d_in[7];   // [768,256]
    const float* bih = (const float*)d_in[8];   // [768]
    const float* bhh = (const float*)d_in[9];   // [768]
    float* out = (float*)d_out;

    // Workspace aliasing identical to the passing R5/R6.
    char* base = (char*)d_ws;
    __hip_bfloat16* w1b  = (__hip_bfloat16*)(base + 0);
    __hip_bfloat16* w2b  = (__hip_bfloat16*)(base + 131072);
    __hip_bfloat16* Dtb  = (__hip_bfloat16*)(base + 262144);
    float*          Mf   = (float*)(base + 0);
    float*          xp   = (float*)(base + 0);
    __hip_bfloat16* a1b  = (__hip_bfloat16*)(base + 33554432);
    __hip_bfloat16* a1db = (__hip_bfloat16*)(base + 41943040);
    __hip_bfloat16* Msb  = (__hip_bfloat16*)(base + 33554432);
    __hip_bfloat16* x1b  = (__hip_bfloat16*)(base + 50331648);
    __hip_bfloat16* x2b  = (__hip_bfloat16*)(base + 58720256);
    __hip_bfloat16* ctxb = (__hip_bfloat16*)(base + 58720256);
    __hip_bfloat16* x2tb = (__hip_bfloat16*)(base + 67108864);
    __hip_bfloat16* a2b  = (__hip_bfloat16*)(base + 75497472);
    __hip_bfloat16* wihb = (__hip_bfloat16*)(base + 75497472);

    dim3 blk(256);

    f2b<<<dim3(4096), blk, 0, stream>>>(x1, x1b, 4194304);
    f2b<<<dim3(4096), blk, 0, stream>>>(x2, x2b, 4194304);
    f2b<<<dim3(64),   blk, 0, stream>>>(w1, w1b, 65536);
    f2b<<<dim3(64),   blk, 0, stream>>>(w2, w2b, 65536);
    tr_f2b<<<dim3(8, 16, 32), blk, 0, stream>>>(x2, x2tb, 512, 256, 131072, 131072);
    tr_f2b<<<dim3(8, 8, 1),   blk, 0, stream>>>(Dm, Dtb, 256, 256, 0, 0);

    gemm_bf16<<<dim3(2, 128, 1), blk, 0, stream>>>(
        x1b, 256, 0, w1b, 256, 0, a1b, 256, 0, 256,
        nullptr, nullptr, 0, 1, 0, 1);
    gemm_bf16<<<dim3(2, 128, 1), blk, 0, stream>>>(
        x2b, 256, 0, w2b, 256, 0, a2b, 256, 0, 256,
        nullptr, nullptr, 0, 1, 0, 1);
    gemm_bf16<<<dim3(2, 128, 1), blk, 0, stream>>>(
        a1b, 256, 0, Dtb, 256, 0, a1db, 256, 0, 256,
        nullptr, nullptr, 0, 0, 0, 1);
    gemm_bf16<<<dim3(4, 4, 32), blk, 0, stream>>>(
        a1db, 256, 131072, a2b, 256, 131072, Mf, 512, 262144, 256,
        nullptr, Wm, 512, 0, 0, 0);
    f2b<<<dim3(384), blk, 0, stream>>>(wih, wihb, 393216);
    softmax_dim1<<<dim3(2, 32), blk, 0, stream>>>(Mf, Msb);
    gemm_bf16<<<dim3(2, 4, 32), blk, 0, stream>>>(
        Msb, 512, 262144, x2tb, 512, 131072, ctxb, 256, 131072, 512,
        nullptr, nullptr, 0, 0, 0, 1);
    gemm_bf16<<<dim3(6, 128, 1), blk, 0, stream>>>(
        x1b, 256, 0, wihb, 512, 0, xp, 768, 0, 256,
        bih, nullptr, 0, 0, 0, 0);
    gemm_bf16<<<dim3(6, 128, 1), blk, 0, stream>>>(
        ctxb, 256, 0, wihb + 256, 512, 0, xp, 768, 0, 256,
        nullptr, nullptr, 0, 0, 1, 0);
    gru_kernel<<<dim3(32), dim3(256), 0, stream>>>(xp, whh, bhh, out);
}

// Round 8
// 1111.351 us; speedup vs baseline: 1.3975x; 1.3975x over previous
//
#include <hip/hip_runtime.h>
#include <hip/hip_bf16.h>
#include <cstdint>
#include <cstddef>

// ---------------------------------------------------------------------------
// EnrichAttention: B=32, L1=L2=512, H=A=256, 3H=768, 2H=512
// R8: GRU = R6 768-thread structure + R7 named-H2x4 SSA weight storage
//     (32 values = 128 VGPRs/thread, inside the 170-reg budget @3 waves/SIMD).
//     GEMM/MFMA pipeline identical to R5/R6.
// ---------------------------------------------------------------------------

typedef _Float16 h2 __attribute__((ext_vector_type(2)));
typedef short s8v __attribute__((ext_vector_type(8)));    // 8 bf16 (4 VGPRs)
typedef float f4v __attribute__((ext_vector_type(4)));    // MFMA accumulator
struct alignas(16) H2x4 { h2 a, b, c, d; };

#if __has_builtin(__builtin_amdgcn_fdot2)
#define FDOT2(a, b, c) __builtin_amdgcn_fdot2((a), (b), (c), false)
#else
#define FDOT2(a, b, c) ((c) + (float)(a)[0] * (float)(b)[0] + (float)(a)[1] * (float)(b)[1])
#endif

#if __has_builtin(__builtin_amdgcn_sched_barrier)
#define SCHED_FENCE() __builtin_amdgcn_sched_barrier(0)
#else
#define SCHED_FENCE() asm volatile("" ::: "memory")
#endif

// Workgroup barrier waiting only on LDS (lgkmcnt). Only hh/hp (LDS) carry
// cross-thread deps in the GRU loop. (Validated R2/R5/R6/R7.)
__device__ __forceinline__ void bar_lds() {
    asm volatile("s_waitcnt lgkmcnt(0)\n\ts_barrier" ::: "memory");
}

__device__ __forceinline__ float fast_exp(float x) {
#if __has_builtin(__builtin_amdgcn_exp2f)
    return __builtin_amdgcn_exp2f(x * 1.44269504f);
#else
    return __expf(x);
#endif
}
__device__ __forceinline__ float fast_rcp(float x) {
#if __has_builtin(__builtin_amdgcn_rcpf)
    return __builtin_amdgcn_rcpf(x);
#else
    return 1.f / x;
#endif
}
__device__ __forceinline__ float fast_sig(float x) { return fast_rcp(1.f + fast_exp(-x)); }
__device__ __forceinline__ float fast_tanh(float x) {
    return 1.f - 2.f * fast_rcp(1.f + fast_exp(2.f * x));
}

// ---------------------------------------------------------------------------
// MFMA bf16 NT GEMM (verified R5): C[M,N] = A[M,K] * B[N,K]^T.
// ---------------------------------------------------------------------------
__global__ __launch_bounds__(256) void gemm_bf16(
    const __hip_bfloat16* __restrict__ A, int lda, long long sA,
    const __hip_bfloat16* __restrict__ B, int ldb, long long sB,
    void* __restrict__ C, int ldc, long long sC,
    int K,
    const float* __restrict__ bias,
    const float* __restrict__ emul, int ldmul,
    int relu, int accum, int out_bf16)
{
    __shared__ short As[128][40];
    __shared__ short Bs[128][40];

    const int tid  = threadIdx.x;
    const int wave = tid >> 6, lane = tid & 63;
    const int quad = lane >> 4, l16 = lane & 15;
    const int wrow = (wave >> 1) * 64, wcol = (wave & 1) * 64;
    const int m0 = blockIdx.y * 128, n0 = blockIdx.x * 128;

    const short* Ab = (const short*)A + (size_t)blockIdx.z * sA;
    const short* Bb = (const short*)B + (size_t)blockIdx.z * sB;

    f4v acc[4][4];
#pragma unroll
    for (int i = 0; i < 4; ++i)
#pragma unroll
        for (int j = 0; j < 4; ++j) acc[i][j] = 0.f;

    const int r0 = tid >> 2,        s0 = (tid & 3) * 8;
    const int r1 = (tid + 256) >> 2, s1 = ((tid + 256) & 3) * 8;

    for (int k0 = 0; k0 < K; k0 += 32) {
        *(s8v*)&As[r0][s0] = *(const s8v*)(Ab + (size_t)(m0 + r0) * lda + k0 + s0);
        *(s8v*)&As[r1][s1] = *(const s8v*)(Ab + (size_t)(m0 + r1) * lda + k0 + s1);
        *(s8v*)&Bs[r0][s0] = *(const s8v*)(Bb + (size_t)(n0 + r0) * ldb + k0 + s0);
        *(s8v*)&Bs[r1][s1] = *(const s8v*)(Bb + (size_t)(n0 + r1) * ldb + k0 + s1);
        __syncthreads();

        s8v af[4], bf[4];
#pragma unroll
        for (int i = 0; i < 4; ++i)
            af[i] = *(const s8v*)&As[wrow + i * 16 + l16][quad * 8];
#pragma unroll
        for (int j = 0; j < 4; ++j)
            bf[j] = *(const s8v*)&Bs[wcol + j * 16 + l16][quad * 8];
#pragma unroll
        for (int i = 0; i < 4; ++i)
#pragma unroll
            for (int j = 0; j < 4; ++j)
                acc[i][j] = __builtin_amdgcn_mfma_f32_16x16x32_bf16(
                    af[i], bf[j], acc[i][j], 0, 0, 0);
        __syncthreads();
    }

    float* Cf = (float*)C + (size_t)blockIdx.z * sC;
    __hip_bfloat16* Cb = (__hip_bfloat16*)C + (size_t)blockIdx.z * sC;
#pragma unroll
    for (int i = 0; i < 4; ++i)
#pragma unroll
        for (int j = 0; j < 4; ++j)
#pragma unroll
            for (int r = 0; r < 4; ++r) {
                const int m = m0 + wrow + i * 16 + quad * 4 + r;
                const int n = n0 + wcol + j * 16 + l16;
                float v = acc[i][j][r];
                if (bias)  v += bias[n];
                if (accum) v += Cf[(size_t)m * ldc + n];
                if (emul)  v *= emul[(size_t)m * ldmul + n];
                if (relu)  v = fmaxf(v, 0.f);
                if (out_bf16) Cb[(size_t)m * ldc + n] = __float2bfloat16(v);
                else          Cf[(size_t)m * ldc + n] = v;
            }
}

// fp32 -> bf16 elementwise (n % 4 == 0)
__global__ __launch_bounds__(256) void f2b(
    const float* __restrict__ s, __hip_bfloat16* __restrict__ d, int n)
{
    const int i = (blockIdx.x * 256 + threadIdx.x) * 4;
    if (i < n) {
        float4 v = *(const float4*)(s + i);
        d[i + 0] = __float2bfloat16(v.x);
        d[i + 1] = __float2bfloat16(v.y);
        d[i + 2] = __float2bfloat16(v.z);
        d[i + 3] = __float2bfloat16(v.w);
    }
}

// fp32 [Z][R][C] -> bf16 [Z][C][R] tiled transpose
__global__ __launch_bounds__(256) void tr_f2b(
    const float* __restrict__ src, __hip_bfloat16* __restrict__ dst,
    int R, int C, long long sS, long long sD)
{
    __shared__ float t[32][33];
    const int r0 = blockIdx.y * 32, c0 = blockIdx.x * 32;
    const int tx = threadIdx.x & 31, ty = threadIdx.x >> 5;
    const float* S = src + (size_t)blockIdx.z * sS;
    __hip_bfloat16* Dd = dst + (size_t)blockIdx.z * sD;
#pragma unroll
    for (int i = 0; i < 32; i += 8)
        t[ty + i][tx] = S[(size_t)(r0 + ty + i) * C + c0 + tx];
    __syncthreads();
#pragma unroll
    for (int i = 0; i < 32; i += 8)
        Dd[(size_t)(c0 + ty + i) * R + r0 + tx] = __float2bfloat16(t[tx][ty + i]);
}

// softmax over axis=1 (i) for each (b, j): fp32 in, bf16 out
__global__ __launch_bounds__(256) void softmax_dim1(
    const float* __restrict__ Mf, __hip_bfloat16* __restrict__ Ms)
{
    const int j = blockIdx.x * 256 + threadIdx.x;
    const float* base = Mf + (size_t)blockIdx.y * 262144;
    __hip_bfloat16* ob = Ms + (size_t)blockIdx.y * 262144;

    float mx = -1e30f;
    for (int i = 0; i < 512; ++i)
        mx = fmaxf(mx, base[(size_t)i * 512 + j]);
    float s = 0.f;
    for (int i = 0; i < 512; ++i)
        s += __expf(base[(size_t)i * 512 + j] - mx);
    const float inv = 1.f / s;
    for (int i = 0; i < 512; ++i)
        ob[(size_t)i * 512 + j] =
            __float2bfloat16(__expf(base[(size_t)i * 512 + j] - mx) * inv);
}

// ---------------------------------------------------------------------------
// GRU R8: 768 threads/WG (12 waves, 3/SIMD, 170-VGPR budget), one WG/batch.
// Thread o owns whh row o as 32 NAMED H2x4 SSA values (128 VGPRs) — the
// storage form R7 proved both correctness-clean and residency-forcing.
// hp[] LDS exchange + o<128 gate epilogue as in the passing R2/R6.
// ---------------------------------------------------------------------------
#define FOR32(M) \
  M(0) M(1) M(2) M(3) M(4) M(5) M(6) M(7) \
  M(8) M(9) M(10) M(11) M(12) M(13) M(14) M(15) \
  M(16) M(17) M(18) M(19) M(20) M(21) M(22) M(23) \
  M(24) M(25) M(26) M(27) M(28) M(29) M(30) M(31)

// load + f16-pack whh cols 8K..8K+7 of this thread's row into named W_K
#define LW(K) \
  H2x4 W_##K; { \
    float4 q0 = wrp[2*(K)], q1 = wrp[2*(K)+1]; \
    W_##K.a[0]=(_Float16)q0.x; W_##K.a[1]=(_Float16)q0.y; \
    W_##K.b[0]=(_Float16)q0.z; W_##K.b[1]=(_Float16)q0.w; \
    W_##K.c[0]=(_Float16)q1.x; W_##K.c[1]=(_Float16)q1.y; \
    W_##K.d[0]=(_Float16)q1.z; W_##K.d[1]=(_Float16)q1.w; } \
  if (((K) & 3) == 3) SCHED_FENCE();

// dot chunk K (h dims 8K..8K+7) into 4 accumulators
#define DOTK(K) { H2x4 v = hvv[K]; \
    a0 = FDOT2(W_##K.a, v.a, a0); a1 = FDOT2(W_##K.b, v.b, a1); \
    a2 = FDOT2(W_##K.c, v.c, a2); a3 = FDOT2(W_##K.d, v.d, a3); }

__global__
__attribute__((amdgpu_flat_work_group_size(768, 768)))
__attribute__((amdgpu_waves_per_eu(3, 3)))
void gru_kernel(
    const float* __restrict__ xproj,   // [B, T, 768]
    const float* __restrict__ whh,     // [768, 256]
    const float* __restrict__ bhh,     // [768]
    float* __restrict__ out)           // [B, T, 256]
{
    const int b = blockIdx.x;
    const int o = threadIdx.x;

    __shared__ __align__(16) h2 hh[128];   // h state, f16-packed
    __shared__ float hp[768];              // h @ whh^T + bhh

    const float4* wrp = (const float4*)(whh + (size_t)o * 256);
    FOR32(LW)

    const float bias_o = bhh[o];
    const float* xb_base = xproj + (size_t)b * 512 * 768;

    float hA = 0.f, hB = 0.f;
    float2 xr, xz, xn;
    if (o < 128) {
        h2 z; z[0] = (_Float16)0.f; z[1] = (_Float16)0.f;
        hh[o] = z;
        const float2* r0 = (const float2*)xb_base;
        xr = r0[o]; xz = r0[128 + o]; xn = r0[256 + o];
    }
    bar_lds();

    for (int t = 0; t < 512; ++t) {
        float a0 = bias_o, a1 = 0.f, a2 = 0.f, a3 = 0.f;
        const H2x4* hvv = (const H2x4*)hh;
        FOR32(DOTK)
        hp[o] = (a0 + a1) + (a2 + a3);
        bar_lds();

        if (o < 128) {
            const int tn = (t + 1) & 511;
            const float2* rn = (const float2*)(xb_base + (size_t)tn * 768);
            float2 nr = rn[o], nz = rn[128 + o], nn = rn[256 + o];

            float2 hr = *(const float2*)&hp[2 * o];
            float2 hz = *(const float2*)&hp[256 + 2 * o];
            float2 hn = *(const float2*)&hp[512 + 2 * o];

            float r0 = fast_sig(xr.x + hr.x), r1 = fast_sig(xr.y + hr.y);
            float z0 = fast_sig(xz.x + hz.x), z1 = fast_sig(xz.y + hz.y);
            float n0 = fast_tanh(xn.x + r0 * hn.x), n1 = fast_tanh(xn.y + r1 * hn.y);
            float nh0 = (1.f - z0) * n0 + z0 * hA;
            float nh1 = (1.f - z1) * n1 + z1 * hB;
            hA = nh0; hB = nh1;

            h2 p; p[0] = (_Float16)nh0; p[1] = (_Float16)nh1;
            hh[o] = p;
            ((float2*)(out + ((size_t)b * 512 + t) * 256))[o] = make_float2(nh0, nh1);

            xr = nr; xz = nz; xn = nn;
        }
        bar_lds();
    }
}
#undef DOTK
#undef LW
#undef FOR32

extern "C" void kernel_launch(void* const* d_in, const int* in_sizes, int n_in,
                              void* d_out, int out_size, void* d_ws, size_t ws_size,
                              hipStream_t stream)
{
    (void)in_sizes; (void)n_in; (void)out_size; (void)ws_size;

    const float* x1  = (const float*)d_in[0];   // [32,512,256]
    const float* x2  = (const float*)d_in[1];   // [32,512,256]
    const float* w1  = (const float*)d_in[2];   // [256,256]
    const float* w2  = (const float*)d_in[3];   // [256,256]
    const float* Dm  = (const float*)d_in[4];   // [256,256]
    const float* Wm  = (const float*)d_in[5];   // [512,512]
    const float* wih = (const float*)d_in[6];   // [768,512]
    const float* whh = (const float*)d_in[7];   // [768,256]
    const float* bih = (const float*)d_in[8];   // [768]
    const float* bhh = (const float*)d_in[9];   // [768]
    float* out = (float*)d_out;

    // Workspace aliasing identical to the passing R5/R6.
    char* base = (char*)d_ws;
    __hip_bfloat16* w1b  = (__hip_bfloat16*)(base + 0);
    __hip_bfloat16* w2b  = (__hip_bfloat16*)(base + 131072);
    __hip_bfloat16* Dtb  = (__hip_bfloat16*)(base + 262144);
    float*          Mf   = (float*)(base + 0);
    float*          xp   = (float*)(base + 0);
    __hip_bfloat16* a1b  = (__hip_bfloat16*)(base + 33554432);
    __hip_bfloat16* a1db = (__hip_bfloat16*)(base + 41943040);
    __hip_bfloat16* Msb  = (__hip_bfloat16*)(base + 33554432);
    __hip_bfloat16* x1b  = (__hip_bfloat16*)(base + 50331648);
    __hip_bfloat16* x2b  = (__hip_bfloat16*)(base + 58720256);
    __hip_bfloat16* ctxb = (__hip_bfloat16*)(base + 58720256);
    __hip_bfloat16* x2tb = (__hip_bfloat16*)(base + 67108864);
    __hip_bfloat16* a2b  = (__hip_bfloat16*)(base + 75497472);
    __hip_bfloat16* wihb = (__hip_bfloat16*)(base + 75497472);

    dim3 blk(256);

    f2b<<<dim3(4096), blk, 0, stream>>>(x1, x1b, 4194304);
    f2b<<<dim3(4096), blk, 0, stream>>>(x2, x2b, 4194304);
    f2b<<<dim3(64),   blk, 0, stream>>>(w1, w1b, 65536);
    f2b<<<dim3(64),   blk, 0, stream>>>(w2, w2b, 65536);
    tr_f2b<<<dim3(8, 16, 32), blk, 0, stream>>>(x2, x2tb, 512, 256, 131072, 131072);
    tr_f2b<<<dim3(8, 8, 1),   blk, 0, stream>>>(Dm, Dtb, 256, 256, 0, 0);

    gemm_bf16<<<dim3(2, 128, 1), blk, 0, stream>>>(
        x1b, 256, 0, w1b, 256, 0, a1b, 256, 0, 256,
        nullptr, nullptr, 0, 1, 0, 1);
    gemm_bf16<<<dim3(2, 128, 1), blk, 0, stream>>>(
        x2b, 256, 0, w2b, 256, 0, a2b, 256, 0, 256,
        nullptr, nullptr, 0, 1, 0, 1);
    gemm_bf16<<<dim3(2, 128, 1), blk, 0, stream>>>(
        a1b, 256, 0, Dtb, 256, 0, a1db, 256, 0, 256,
        nullptr, nullptr, 0, 0, 0, 1);
    gemm_bf16<<<dim3(4, 4, 32), blk, 0, stream>>>(
        a1db, 256, 131072, a2b, 256, 131072, Mf, 512, 262144, 256,
        nullptr, Wm, 512, 0, 0, 0);
    f2b<<<dim3(384), blk, 0, stream>>>(wih, wihb, 393216);
    softmax_dim1<<<dim3(2, 32), blk, 0, stream>>>(Mf, Msb);
    gemm_bf16<<<dim3(2, 4, 32), blk, 0, stream>>>(
        Msb, 512, 262144, x2tb, 512, 131072, ctxb, 256, 131072, 512,
        nullptr, nullptr, 0, 0, 0, 1);
    gemm_bf16<<<dim3(6, 128, 1), blk, 0, stream>>>(
        x1b, 256, 0, wihb, 512, 0, xp, 768, 0, 256,
        bih, nullptr, 0, 0, 0, 0);
    gemm_bf16<<<dim3(6, 128, 1), blk, 0, stream>>>(
        ctxb, 256, 0, wihb + 256, 512, 0, xp, 768, 0, 256,
        nullptr, nullptr, 0, 0, 1, 0);
    gru_kernel<<<dim3(32), dim3(768), 0, stream>>>(xp, whh, bhh, out);
}